// Round 7
// baseline (50.080 us; speedup 1.0000x reference)
//
#include <hip/hip_runtime.h>

// Problem geometry (fixed by reference setup_inputs()):
//   src: [B=4, N=8192, 3] f32
//   dst: [B=4, S=2048, 3] f32
//   out: [B, N, S] f32 = softmax_S( exp( -0.5 * ||src_n - dst_s|| ) )
#define BB 4
#define NN 8192
#define SS 2048
#define ROWS 2        // rows per iteration (VGPR budget: v[2][8]=16 regs)
#define ITERS 8       // row-pairs per block -> 16-row contiguous stripe/block

#define L2E  1.4426950408889634f   // log2(e)
#define NL2E 0.7213475204444817f   // 0.5 * log2(e)

typedef float f32x4 __attribute__((ext_vector_type(4)));

// Persistent-stripe kernel: 512x4 blocks, each owns 16 consecutive rows
// (128 KB contiguous output). dst coords register-resident, loaded ONCE and
// reused across all 16 rows. One barrier per 2-row iteration (wsum
// double-buffered). Keeps VGPR <= 64 -> 8 waves/SIMD.
__global__ __launch_bounds__(256, 8)
void gauss_softmax_kernel(const float* __restrict__ src,
                          const float* __restrict__ dst,
                          float* __restrict__ out) {
    const int b   = blockIdx.y;
    const int tid = threadIdx.x;
    const int nb  = blockIdx.x * (ROWS * ITERS);   // first row of this stripe

    const float* dstb = dst + (size_t)b * SS * 3;

    // Load this thread's 8 dst points into registers, once per block.
    float px[8], py[8], pz[8];
    #pragma unroll
    for (int k = 0; k < 2; ++k) {
        const int s0 = tid * 4 + k * 1024;  // 48B-aligned: tid*48 + k*12288
        const f32x4 p0 = *reinterpret_cast<const f32x4*>(dstb + (size_t)s0 * 3 + 0);
        const f32x4 p1 = *reinterpret_cast<const f32x4*>(dstb + (size_t)s0 * 3 + 4);
        const f32x4 p2 = *reinterpret_cast<const f32x4*>(dstb + (size_t)s0 * 3 + 8);
        px[k*4+0] = p0.x; py[k*4+0] = p0.y; pz[k*4+0] = p0.z;
        px[k*4+1] = p0.w; py[k*4+1] = p1.x; pz[k*4+1] = p1.y;
        px[k*4+2] = p1.z; py[k*4+2] = p1.w; pz[k*4+2] = p2.x;
        px[k*4+3] = p2.y; py[k*4+3] = p2.z; pz[k*4+3] = p2.w;
    }

    __shared__ float wsum[2][ROWS][4];   // double-buffered: 1 barrier/iter
    const int lane = tid & 63;
    const int wid  = tid >> 6;

    for (int it = 0; it < ITERS; ++it) {
        const int n0 = nb + it * ROWS;
        const int buf = it & 1;
        float v[ROWS][8];

        #pragma unroll
        for (int r = 0; r < ROWS; ++r) {
            const size_t row = (size_t)(b * NN + n0 + r);
            const float sx = src[row * 3 + 0];
            const float sy = src[row * 3 + 1];
            const float sz = src[row * 3 + 2];

            float local = 0.0f;
            #pragma unroll
            for (int j = 0; j < 8; ++j) {
                const float dx = sx - px[j];
                const float dy = sy - py[j];
                const float dz = sz - pz[j];
                const float d2 = fmaxf(dx * dx + dy * dy + dz * dz, 1e-12f);
                const float dist = __builtin_amdgcn_sqrtf(d2);
                // exp(exp(-0.5*dist)) = exp2(L2E * exp2(-0.5*L2E*dist))
                const float inner = __builtin_amdgcn_exp2f(-NL2E * dist);
                const float t = __builtin_amdgcn_exp2f(L2E * inner);
                v[r][j] = t;
                local += t;
            }

            // wave64 butterfly reduce
            #pragma unroll
            for (int off = 32; off >= 1; off >>= 1)
                local += __shfl_down(local, off, 64);
            if (lane == 0) wsum[buf][r][wid] = local;
        }

        __syncthreads();   // wsum[buf] ready; wsum[buf^1] free for next iter

        #pragma unroll
        for (int r = 0; r < ROWS; ++r) {
            const float inv = __builtin_amdgcn_rcpf(wsum[buf][r][0] + wsum[buf][r][1] +
                                                    wsum[buf][r][2] + wsum[buf][r][3]);
            float* outp = out + (size_t)(b * NN + n0 + r) * SS;
            #pragma unroll
            for (int k = 0; k < 2; ++k) {
                const int s0 = tid * 4 + k * 1024;
                f32x4 o;
                o.x = v[r][k*4+0] * inv;
                o.y = v[r][k*4+1] * inv;
                o.z = v[r][k*4+2] * inv;
                o.w = v[r][k*4+3] * inv;
                *reinterpret_cast<f32x4*>(outp + s0) = o;
            }
        }
    }
}

extern "C" void kernel_launch(void* const* d_in, const int* in_sizes, int n_in,
                              void* d_out, int out_size, void* d_ws, size_t ws_size,
                              hipStream_t stream) {
    const float* src = (const float*)d_in[0];  // [4, 8192, 3]
    const float* dst = (const float*)d_in[1];  // [4, 2048, 3]
    float* out = (float*)d_out;                // [4, 8192, 2048]

    dim3 grid(NN / (ROWS * ITERS), BB);        // 512 x 4 blocks, persistent stripes
    dim3 block(256);
    gauss_softmax_kernel<<<grid, block, 0, stream>>>(src, dst, out);
}

// Round 8
// 46.170 us; speedup vs baseline: 1.0847x; 1.0847x over previous
//
#include <hip/hip_runtime.h>

// Problem geometry (fixed by reference setup_inputs()):
//   src: [B=4, N=8192, 3] f32
//   dst: [B=4, S=2048, 3] f32
//   out: [B, N, S] f32 = softmax_S( exp( -0.5 * ||src_n - dst_s|| ) )
//
// FINAL kernel (best measured config, R2 structure):
//   - one block per 4 consecutive rows; 256 threads; 8 s-values/thread
//   - dst coords register-resident (24 VGPR), float4-coalesced loads/stores
//   - fast-path math: v_sqrt_f32 + 2x v_exp_f32 (exp(e^x) = exp2(L2E*exp2(L2E*x)))
//   - absmax 3.8e-6 vs 2.1e-5 threshold
// Measured 48.5 us = 5.5 TB/s effective write BW (88% of measured 6.29 TB/s
// copy ceiling). Occupancy / phase-structure / dispatch-granularity / nt-store
// variants all within +-3% or worse (rounds 4-7): memory-bound roofline.
#define BB 4
#define NN 8192
#define SS 2048
#define ROWS 4   // rows (n-values) per block; dst coords stay in registers

#define L2E  1.4426950408889634f   // log2(e)
#define NL2E 0.7213475204444817f   // 0.5 * log2(e)

typedef float f32x4 __attribute__((ext_vector_type(4)));

__global__ __launch_bounds__(256)
void gauss_softmax_kernel(const float* __restrict__ src,
                          const float* __restrict__ dst,
                          float* __restrict__ out) {
    const int n0  = blockIdx.x * ROWS;
    const int b   = blockIdx.y;
    const int tid = threadIdx.x;

    const float* dstb = dst + (size_t)b * SS * 3;

    // Load this thread's 8 dst points once (registers), reuse across ROWS.
    float px[8], py[8], pz[8];
    #pragma unroll
    for (int k = 0; k < 2; ++k) {
        const int s0 = tid * 4 + k * 1024;  // 48B-aligned: tid*48 + k*12288
        const f32x4 p0 = *reinterpret_cast<const f32x4*>(dstb + (size_t)s0 * 3 + 0);
        const f32x4 p1 = *reinterpret_cast<const f32x4*>(dstb + (size_t)s0 * 3 + 4);
        const f32x4 p2 = *reinterpret_cast<const f32x4*>(dstb + (size_t)s0 * 3 + 8);
        px[k*4+0] = p0.x; py[k*4+0] = p0.y; pz[k*4+0] = p0.z;
        px[k*4+1] = p0.w; py[k*4+1] = p1.x; pz[k*4+1] = p1.y;
        px[k*4+2] = p1.z; py[k*4+2] = p1.w; pz[k*4+2] = p2.x;
        px[k*4+3] = p2.y; py[k*4+3] = p2.z; pz[k*4+3] = p2.w;
    }

    __shared__ float wsum[ROWS][4];
    const int lane = tid & 63;
    const int wid  = tid >> 6;

    float v[ROWS][8];

    #pragma unroll
    for (int r = 0; r < ROWS; ++r) {
        const size_t row = (size_t)(b * NN + n0 + r);
        const float sx = src[row * 3 + 0];
        const float sy = src[row * 3 + 1];
        const float sz = src[row * 3 + 2];

        float local = 0.0f;
        #pragma unroll
        for (int j = 0; j < 8; ++j) {
            const float dx = sx - px[j];
            const float dy = sy - py[j];
            const float dz = sz - pz[j];
            const float d2 = fmaxf(dx * dx + dy * dy + dz * dz, 1e-12f);
            const float dist = __builtin_amdgcn_sqrtf(d2);
            // exp(exp(-0.5*dist)) = exp2(L2E * exp2(-0.5*L2E*dist))
            const float inner = __builtin_amdgcn_exp2f(-NL2E * dist);
            const float t = __builtin_amdgcn_exp2f(L2E * inner);
            v[r][j] = t;
            local += t;
        }

        // wave64 butterfly reduce
        #pragma unroll
        for (int off = 32; off >= 1; off >>= 1)
            local += __shfl_down(local, off, 64);
        if (lane == 0) wsum[r][wid] = local;
    }

    __syncthreads();

    #pragma unroll
    for (int r = 0; r < ROWS; ++r) {
        const float inv = __builtin_amdgcn_rcpf(wsum[r][0] + wsum[r][1] +
                                                wsum[r][2] + wsum[r][3]);
        float* outp = out + (size_t)(b * NN + n0 + r) * SS;
        #pragma unroll
        for (int k = 0; k < 2; ++k) {
            const int s0 = tid * 4 + k * 1024;
            f32x4 o;
            o.x = v[r][k*4+0] * inv;
            o.y = v[r][k*4+1] * inv;
            o.z = v[r][k*4+2] * inv;
            o.w = v[r][k*4+3] * inv;
            *reinterpret_cast<f32x4*>(outp + s0) = o;
        }
    }
}

extern "C" void kernel_launch(void* const* d_in, const int* in_sizes, int n_in,
                              void* d_out, int out_size, void* d_ws, size_t ws_size,
                              hipStream_t stream) {
    const float* src = (const float*)d_in[0];  // [4, 8192, 3]
    const float* dst = (const float*)d_in[1];  // [4, 2048, 3]
    float* out = (float*)d_out;                // [4, 8192, 2048]

    dim3 grid(NN / ROWS, BB);                  // 2048 x 4 blocks
    dim3 block(256);
    gauss_softmax_kernel<<<grid, block, 0, stream>>>(src, dst, out);
}